// Round 11
// baseline (813.895 us; speedup 1.0000x reference)
//
#include <hip/hip_runtime.h>
#include <hip/hip_bf16.h>
#include <math.h>

// ---------------------------------------------------------------------------
// DeepTemplateMatchingModule — round 26.
// vs round 25 (783.7 us, regression): r25's counters cracked the GRU:
// VGPR_Count=76 vs ~180 demand -> removing launch_bounds applied the DEFAULT
// 1024-thread cap (~102 VGPR) and spilled everything (r24's (192,3)=170 cap
// also spilled; spill theory right, both fixes wrong). And the h-broadcast
// (16 ds_read_b128/thread/step ~ 232 LDS instr/CU/step) was the structural
// cost. Fix: v_readlane h-broadcast — lane u already holds h[u] in hown;
// readlane(hown,k) with literal k feeds the FMA's SGPR slot. h[64] array
// GONE (demand ~85 VGPR, no spill under (192,3)); per-step LDS = 1 write +
// 1 ds_read_b128 (gates repacked gx[buf][u][4]); 1 barrier/step (r24-proven
// dbuf). conv2 reverted to r24 geometry (NHI=2 — r25's NHI=3 was part of
// the +20 regression).
// ---------------------------------------------------------------------------

#define DEVI static __device__ __forceinline__
typedef __attribute__((ext_vector_type(8))) short short8;
typedef __attribute__((ext_vector_type(4))) float f32x4;
typedef __attribute__((ext_vector_type(8))) float f32x8;
typedef unsigned short ushort_t;

DEVI float fsig(float x)   { return 1.f / (1.f + __expf(-x)); }
DEVI float ftanh_(float x) { return 2.f / (1.f + __expf(-2.f * x)) - 1.f; }
DEVI float bf2f(ushort_t u) { union { unsigned int i; float f; } v; v.i = ((unsigned int)u) << 16; return v.f; }
DEVI ushort_t f2bf(float f) {
    union { float f; unsigned int i; } v; v.f = f;
    unsigned int r = v.i + 0x7FFF + ((v.i >> 16) & 1);
    return (ushort_t)(r >> 16);
}
DEVI f32x8 bf2f8(short8 s) {
    f32x8 r;
#pragma unroll
    for (int k = 0; k < 8; k++) r[k] = bf2f((ushort_t)s[k]);
    return r;
}
DEVI f32x8 max8(f32x8 a, f32x8 b) {
    f32x8 r;
#pragma unroll
    for (int k = 0; k < 8; k++) r[k] = fmaxf(a[k], b[k]);
    return r;
}
DEVI float rdlane(float v, int lane) {
    union { float f; int i; } a; a.f = v;
    union { int i; float f; } b;
    b.i = __builtin_amdgcn_readlane(a.i, lane);
    return b.f;
}

// async global->LDS, 16 bytes per lane. LDS dest must be lane-linear
// (wave-uniform base + lane*16); global src is per-lane.
DEVI void glds16(const ushort_t* g, ushort_t* l)
{
    __builtin_amdgcn_global_load_lds(
        (const __attribute__((address_space(1))) void*)g,
        (__attribute__((address_space(3))) void*)l, 16, 0, 0);
}

// ---------------- fused weight packs + zsum zero ---------------------------
__global__ void pack_all(const float* __restrict__ w2, const float* __restrict__ w3,
                         const float* __restrict__ l1w,
                         ushort_t* __restrict__ w2p, ushort_t* __restrict__ w3p,
                         ushort_t* __restrict__ l1wp, float* __restrict__ zsum)
{
    const int gid = blockIdx.x * 256 + threadIdx.x;
    const int gsz = gridDim.x * 256;
    for (int idx = gid; idx < 15360; idx += gsz) {
        int kh = idx / 3072, rem = idx % 3072;
        int kw = rem / 512;
        int co = (rem >> 4) & 31, ci = rem & 15;
        float v = (kw < 5) ? w2[((co * 16 + ci) * 5 + kh) * 5 + kw] : 0.f;
        w2p[idx] = f2bf(v);
    }
    for (int idx = gid; idx < 51200; idx += gsz) {
        int kh = idx / 10240, rem = idx % 10240;
        int kw = rem / 2048;
        int co = (rem >> 5) & 63, ci = rem & 31;
        w3p[idx] = f2bf(w3[((co * 32 + ci) * 5 + kh) * 5 + kw]);
    }
    for (int idx = gid; idx < 262144; idx += gsz) {
        int u   = idx & 7;
        int co  = (idx >> 3) & 63;
        int oct = (idx >> 9) & 7;
        int r   = idx >> 12;
        int jj  = oct * 8 + u;
        float v = (jj < 58) ? l1w[co * 3712 + r * 58 + jj] : 0.f;
        l1wp[idx] = f2bf(v);
    }
    for (int idx = gid; idx < 8192; idx += gsz) zsum[idx] = 0.f;
}

// ---------------- conv1: direct from eval/template, writes NHWC bf16 -------
__global__ void conv1_kernel(const float* __restrict__ ev,
                             const float* __restrict__ tmpl,
                             const float* __restrict__ wgt,
                             const float* __restrict__ bias,
                             ushort_t* __restrict__ out, int n0)
{
    const int h0  = blockIdx.x * 4;
    const int w0  = blockIdx.y * 62;
    const int nl  = blockIdx.z;
    const int n   = n0 + nl;
    const int tid = threadIdx.x;
    const int wl  = tid & 63;
    const int cg  = tid >> 6;
    const float* src = (n < 16) ? (ev + (size_t)n * 65536)
                                : (tmpl + (size_t)(n - 16) * 65536);

    __shared__ float tin[8 * 68];
    __shared__ float tw[16 * 25];

    float acc[4][4];
#pragma unroll
    for (int j = 0; j < 4; j++)
#pragma unroll
        for (int hh = 0; hh < 4; hh++) acc[j][hh] = 0.f;

    for (int idx = tid; idx < 528; idx += 256) {
        int cc = idx >> 3, r = idx & 7;
        tin[r * 68 + cc] = src[(w0 + cc) * 512 + h0 + r];
    }
    for (int idx = tid; idx < 400; idx += 256) tw[idx] = wgt[idx];
    __syncthreads();
#pragma unroll
    for (int kh = 0; kh < 5; kh++) {
#pragma unroll
        for (int kw = 0; kw < 5; kw++) {
            float iv[4];
#pragma unroll
            for (int hh = 0; hh < 4; hh++)
                iv[hh] = tin[(hh + kh) * 68 + wl + kw];
#pragma unroll
            for (int j = 0; j < 4; j++) {
                float wv = tw[(cg * 4 + j) * 25 + kh * 5 + kw];
#pragma unroll
                for (int hh = 0; hh < 4; hh++)
                    acc[j][hh] = fmaf(wv, iv[hh], acc[j][hh]);
            }
        }
    }
    if (wl < 62) {
#pragma unroll
        for (int hh = 0; hh < 4; hh++) {
            ushort_t pk[4];
#pragma unroll
            for (int j = 0; j < 4; j++)
                pk[j] = f2bf(acc[j][hh] + bias[cg * 4 + j]);
            ushort_t* dst = out + ((size_t)(nl * 508 + h0 + hh) * 124 + w0 + wl) * 16 + cg * 4;
            *(uint2*)dst = *(uint2*)pk;
        }
    }
}

// ---------------- MFMA implicit-GEMM 5x5 conv (r23 layout, opt. h-pool) ----
template<int CI, int CO, int NF, int MF, int NHI, int W_T, int KSTEPS,
         int KW_TOT, int H_IN, int W_IN, bool PAD2, bool HPOOL, int MAXB>
__global__ __launch_bounds__(256, MAXB) void conv_mfma(
    const ushort_t* __restrict__ in, const ushort_t* __restrict__ wpk,
    const float* __restrict__ bias, ushort_t* __restrict__ out)
{
    constexpr int H_OUT = H_IN - 4;
    constexpr int W_OUT = W_IN - 4;
    constexpr int HALO  = W_T + 6;
    constexpr int OCT   = CI / 8;
    constexpr int AROWS = 4 * NHI + 4;
    constexpr int APL   = AROWS * HALO;
    constexpr int BPL   = KW_TOT * CO;
    constexpr int BTOT  = OCT * BPL;
    constexpr int BSTG  = (BTOT + 255) / 256;
    constexpr int KHOFF = KW_TOT * CO * CI;   // element offset per kh row

    const int h0 = blockIdx.x * (4 * NHI);
    const int w0 = blockIdx.y * W_T;
    const int nl = blockIdx.z;
    const int tid  = threadIdx.x;
    const int wv   = tid >> 6;
    const int lane = tid & 63;
    const int l16  = lane & 15;
    const int kq   = lane >> 4;

    __shared__ __align__(16) ushort_t As[OCT * APL * 8];
    __shared__ __align__(16) ushort_t Bs[BTOT * 8];

    f32x4 acc[NHI][MF][NF];
#pragma unroll
    for (int hi = 0; hi < NHI; hi++)
#pragma unroll
        for (int mi = 0; mi < MF; mi++)
#pragma unroll
            for (int ni = 0; ni < NF; ni++)
                acc[hi][mi][ni] = f32x4{0.f, 0.f, 0.f, 0.f};

    // A tile staged once
    for (int idx = tid; idx < OCT * APL; idx += 256) {
        int oct = idx / APL, e = idx - oct * APL;
        int r = e / HALO, c = e - r * HALO;
        glds16(in + ((size_t)((nl * H_IN + h0 + r) * W_IN + w0 + c)) * CI + oct * 8,
               &As[idx * 8]);
    }

    // B staging addresses hoisted: computed once, reused for all 5 kh rows
    const ushort_t* bsrc[BSTG];
    ushort_t*       bdst[BSTG];
#pragma unroll
    for (int sb = 0; sb < BSTG; sb++) {
        int idx = tid + sb * 256;
        if (idx < BTOT) {
            int oct = idx / BPL, e = idx - oct * BPL;
            int kw = e / CO, co = e - kw * CO;
            bsrc[sb] = wpk + ((size_t)(kw * CO + co)) * CI + oct * 8;
            bdst[sb] = &Bs[idx * 8];
        } else { bsrc[sb] = nullptr; bdst[sb] = nullptr; }
    }

    const int aoct = PAD2 ? (kq & 1) : kq;
    const int kwq  = PAD2 ? (kq >> 1) : 0;

#pragma unroll
    for (int kh = 0; kh < 5; kh++) {
        __syncthreads();
#pragma unroll
        for (int sb = 0; sb < BSTG; sb++)
            if (bsrc[sb]) glds16(bsrc[sb] + kh * KHOFF, bdst[sb]);
        __syncthreads();
#pragma unroll
        for (int st = 0; st < KSTEPS; st++) {
            const int colq = (PAD2 ? st * 2 : st) + kwq;
            short8 bfv[NF];
#pragma unroll
            for (int ni = 0; ni < NF; ni++)
                bfv[ni] = *(const short8*)&Bs[(aoct * BPL + colq * CO + ni * 16 + l16) * 8];
#pragma unroll
            for (int hi = 0; hi < NHI; hi++) {
                short8 af[MF];
#pragma unroll
                for (int mi = 0; mi < MF; mi++)
                    af[mi] = *(const short8*)&As[(aoct * APL + (hi * 4 + wv + kh) * HALO + mi * 16 + l16 + colq) * 8];
#pragma unroll
                for (int mi = 0; mi < MF; mi++)
#pragma unroll
                    for (int ni = 0; ni < NF; ni++)
                        acc[hi][mi][ni] = __builtin_amdgcn_mfma_f32_16x16x32_bf16(
                            af[mi], bfv[ni], acc[hi][mi][ni], 0, 0, 0);
            }
        }
    }

#pragma unroll
    for (int hi = 0; hi < NHI; hi++) {
        const int h = h0 + hi * 4 + wv;
        if (h < H_OUT) {
#pragma unroll
            for (int mi = 0; mi < MF; mi++) {
#pragma unroll
                for (int ni = 0; ni < NF; ni++) {
                    int co = ni * 16 + l16;
                    float bv = bias[co];
                    if constexpr (HPOOL) {
                        const int jw = (w0 + mi * 16 + kq * 4) >> 1;
                        if (jw < 58)
                            out[((size_t)(nl * H_OUT + h) * 58 + jw) * CO + co] =
                                f2bf(fmaxf(acc[hi][mi][ni][0], acc[hi][mi][ni][1]) + bv);
                        if (jw + 1 < 58)
                            out[((size_t)(nl * H_OUT + h) * 58 + jw + 1) * CO + co] =
                                f2bf(fmaxf(acc[hi][mi][ni][2], acc[hi][mi][ni][3]) + bv);
                    } else {
#pragma unroll
                        for (int reg = 0; reg < 4; reg++) {
                            int w = w0 + mi * 16 + kq * 4 + reg;
                            if (w < W_OUT)
                                out[((size_t)(nl * H_OUT + h) * W_OUT + w) * CO + co] =
                                    f2bf(acc[hi][mi][ni][reg] + bv);
                        }
                    }
                }
            }
        }
    }
}

// ---------------- fused pool: vertical 5-max + transpose -> NCHW-flat ------
__global__ __launch_bounds__(512) void pool_fused(const ushort_t* __restrict__ a3h,
                                                  ushort_t* __restrict__ pooled)
{
    const int nl = blockIdx.y;
    const int s0 = blockIdx.x * 16;      // 31 blocks x 16 = 496
    const int t  = threadIdx.x;
    __shared__ ushort_t L[4 * 3712];

    const int j = t >> 3, oct = t & 7;
    const ushort_t* base = a3h + (size_t)nl * 1856000 + (size_t)j * 64 + oct * 8;
    ushort_t* dst = pooled + (size_t)nl * 1841152;

#define LOADROW(rr) bf2f8(*(const short8*)(base + (size_t)(rr) * 3712))
    f32x8 w0, w1, w2v, w3v;
    if (t < 464) {
        w0  = LOADROW(s0);
        w1  = LOADROW(s0 + 1);
        w2v = LOADROW(s0 + 2);
        w3v = LOADROW(s0 + 3);
    }
    for (int g = 0; g < 4; g++) {
        if (t < 464) {
#pragma unroll
            for (int k = 0; k < 4; k++) {
                int s = s0 + g * 4 + k;
                f32x8 w4 = LOADROW(s + 4);
                f32x8 mx = max8(max8(max8(w0, w1), max8(w2v, w3v)), w4);
#pragma unroll
                for (int u = 0; u < 8; u++)
                    L[k * 3712 + (oct * 8 + u) * 58 + j] = f2bf(mx[u]);
                w0 = w1; w1 = w2v; w2v = w3v; w3v = w4;
            }
        }
        __syncthreads();
        const int sg = s0 + g * 4;
        for (int e = t; e < 14848; e += 512) {
            int k = e / 3712, r = e - k * 3712;
            int c = r / 58, jj = r - c * 58;
            dst[(size_t)c * 28768 + (sg + k) * 58 + jj] = L[e];
        }
        __syncthreads();
    }
#undef LOADROW
}

// ---------------- lin1: M=64 N=64 K=1024/block MFMA, k-split x4 ------------
__global__ __launch_bounds__(256) void lin1_mfma(
    const ushort_t* __restrict__ pooled, const ushort_t* __restrict__ l1wp,
    float* __restrict__ xb, int n0, int RT)
{
    const int mt  = blockIdx.x;
    const int kqb = blockIdx.y;          // 4 k-quarters
    const int r0  = mt * 64;
    const int t   = threadIdx.x;
    const int wv  = t >> 6, lane = t & 63, l16 = lane & 15, kq = lane >> 4;

    __shared__ __align__(16) ushort_t As[8 * 64 * 8];  // [oct][row]
    __shared__ __align__(16) ushort_t Bs[8 * 64 * 8];  // [oct][co]

    f32x4 acc[4];
#pragma unroll
    for (int ni = 0; ni < 4; ni++) acc[ni] = f32x4{0.f, 0.f, 0.f, 0.f};

    for (int kb = 0; kb < 16; kb++) {
        const int k0 = kqb * 1024 + kb * 64;
        const int r  = k0 >> 6;
        __syncthreads();
        // A: coalesced — 8 lanes (oct 0..7) read 128B contiguous per row
        for (int idx = t; idx < 512; idx += 256) {
            int row = idx >> 3, oct = idx & 7;
            int rr = r0 + row;
            short8 v = short8{0, 0, 0, 0, 0, 0, 0, 0};
            if (rr < RT)
                v = *(const short8*)(pooled + (size_t)rr * 3712 + r * 58 + oct * 8);
            *(short8*)&As[(oct * 64 + row) * 8] = v;
        }
        // B: l1wp packed in staging-linear order [r][oct][co] -> glds16
        // sources are lane-consecutive, dest is lane-linear.
        for (int idx = t; idx < 512; idx += 256)
            glds16(l1wp + ((size_t)r * 512 + idx) * 8, &Bs[idx * 8]);
        __syncthreads();
#pragma unroll
        for (int st = 0; st < 2; st++) {
            short8 af = *(const short8*)&As[((st * 4 + kq) * 64 + wv * 16 + l16) * 8];
#pragma unroll
            for (int ni = 0; ni < 4; ni++) {
                short8 bfv = *(const short8*)&Bs[((st * 4 + kq) * 64 + ni * 16 + l16) * 8];
                acc[ni] = __builtin_amdgcn_mfma_f32_16x16x32_bf16(af, bfv, acc[ni], 0, 0, 0);
            }
        }
    }
#pragma unroll
    for (int ni = 0; ni < 4; ni++) {
        int co = ni * 16 + l16;
#pragma unroll
        for (int reg = 0; reg < 4; reg++) {
            int rr = r0 + wv * 16 + kq * 4 + reg;
            if (rr < RT)
                atomicAdd(&xb[((size_t)n0 * 496 + rr) * 64 + co], acc[ni][reg]);
        }
    }
}

// ---------------- gi = (x + l1b) @ W_ih^T + b_ih  (coalesced W staging) ----
__global__ __launch_bounds__(192) void gi_kernel(
    const float* __restrict__ x, const float* __restrict__ Wih,
    const float* __restrict__ bih, const float* __restrict__ l1b,
    float* __restrict__ gi)
{
    const int r0 = blockIdx.x * 64;
    const int j  = threadIdx.x; // 192
    __shared__ float wls[192 * 65];
    __shared__ float xl[64 * 64];

    for (int idx = j; idx < 12288; idx += 192)
        wls[(idx >> 6) * 65 + (idx & 63)] = Wih[idx];
    for (int idx = j; idx < 4096; idx += 192)
        xl[idx] = x[(size_t)r0 * 64 + idx] + l1b[idx & 63];
    __syncthreads();

    float w[64];
#pragma unroll
    for (int d = 0; d < 64; d++) w[d] = wls[j * 65 + d];
    const float bj = bih[j];

    for (int s = 0; s < 64; s++) {
        float a = bj;
#pragma unroll
        for (int d = 0; d < 64; d++) a = fmaf(w[d], xl[s * 64 + d], a);
        gi[(size_t)(r0 + s) * 192 + j] = a;
    }
}

// ---------------- chunk-parallel GRU: readlane h-broadcast -----------------
// Lane u holds h[u] in hown; h[k] reaches the FMA as an SGPR via
// v_readlane (literal k). No h[] array (no spill), no LDS h-broadcast.
// Per-step LDS: 1 write + 1 ds_read_b128 (gates packed gx[buf][u][4]);
// 1 barrier (double-buffered gx bounds wave skew).
__global__ __launch_bounds__(192, 3) void gru_kernel(
    const float* __restrict__ gi, const float* __restrict__ Whh,
    const float* __restrict__ bhh, float* __restrict__ Eo,
    float* __restrict__ To)
{
    const int c  = blockIdx.x;          // 992 = 2 x 496
    const int br = (c >= 496) ? 1 : 0;
    const int q  = c - br * 496;
    const int j  = threadIdx.x;         // 0..191
    const int wvid = j >> 6;            // wave 0..2 (r,z,n gate rows)
    const int u    = j & 63;            // unit id
    const float* gb = gi + (size_t)br * 7936 * 192;
    float* out = br ? To : Eo;

    float w[64];
#pragma unroll
    for (int k = 0; k < 64; k++) w[k] = Whh[j * 64 + k];
    const float bh = bhh[j];

    __shared__ __align__(16) float gx[2][64][4];  // [buf][unit][r,z,n_gh,n_g]

    float hown = 0.f;                   // h[u]

    const int cs  = q * 16;
    int start = cs - 96;
    if (start < 0) start = 0;
    const int end = cs + 16;

    const bool isN = (wvid == 2);

    float pg[4];
#pragma unroll
    for (int uu = 0; uu < 4; uu++) {
        int s = start + uu;
        pg[uu] = (s < end) ? gb[(size_t)s * 192 + j] : 0.f;
    }

    int s = start;
    int buf = 0;
    while (s < end) {
#pragma unroll
        for (int uu = 0; uu < 4; uu++) {
            if (s < end) {
                float g = pg[uu];
                int sp = s + 4;
                if (sp < end) pg[uu] = gb[(size_t)sp * 192 + j];
                float a0 = bh, a1 = 0.f, a2 = 0.f, a3 = 0.f;
#pragma unroll
                for (int k = 0; k < 64; k += 4) {
                    a0 = fmaf(w[k],     rdlane(hown, k),     a0);
                    a1 = fmaf(w[k + 1], rdlane(hown, k + 1), a1);
                    a2 = fmaf(w[k + 2], rdlane(hown, k + 2), a2);
                    a3 = fmaf(w[k + 3], rdlane(hown, k + 3), a3);
                }
                float gh = (a0 + a1) + (a2 + a3);
                if (isN) {
                    gx[buf][u][2] = gh;
                    gx[buf][u][3] = g;
                } else {
                    gx[buf][u][wvid] = gh + g;
                }
                __syncthreads();
                float4 gv = *(const float4*)gx[buf][u];
                float r  = fsig(gv.x);
                float z  = fsig(gv.y);
                float nv = ftanh_(gv.w + r * gv.z);
                float hn = (1.f - z) * nv + z * hown;
                hown = hn;
                if (wvid == 0 && s >= cs) out[(size_t)s * 64 + u] = hn;
                buf ^= 1;
                s++;
            }
        }
    }
}

// ---------------- scores + fused column exp-sum (stores P = exp(S)) --------
__global__ void scores_kernel(const float* __restrict__ E,
                              const float* __restrict__ Tm,
                              float* __restrict__ S,
                              float* __restrict__ zsum)
{
    const int b  = blockIdx.z;
    const int m0 = blockIdx.y * 32;
    const int n0 = blockIdx.x * 64;
    const int t  = threadIdx.x;
    const int nl = t & 63, mg = t >> 6;
    __shared__ float El[32 * 64];
    __shared__ float Tms[64 * 65];

    for (int idx = t; idx < 2048; idx += 256) {
        int r = idx >> 6, d = idx & 63;
        int m = m0 + r;
        El[idx] = (m < 496) ? E[((size_t)b * 496 + m) * 64 + d] : 0.f;
    }
    for (int idx = t; idx < 4096; idx += 256) {
        int r = idx >> 6, d = idx & 63;
        int n = n0 + r;
        Tms[d * 65 + r] = (n < 496) ? Tm[((size_t)b * 496 + n) * 64 + d] : 0.f;
    }
    __syncthreads();

    float acc[8];
#pragma unroll
    for (int j = 0; j < 8; j++) acc[j] = 0.f;
#pragma unroll 4
    for (int d = 0; d < 64; d++) {
        float tv = Tms[d * 65 + nl];
#pragma unroll
        for (int j = 0; j < 8; j++)
            acc[j] = fmaf(El[(mg * 8 + j) * 64 + d], tv, acc[j]);
    }
    int n = n0 + nl;
    if (n < 496) {
        float lsum = 0.f;
#pragma unroll
        for (int j = 0; j < 8; j++) {
            int m = m0 + mg * 8 + j;
            if (m < 496) {
                float p = __expf(acc[j]);
                S[((size_t)b * 496 + m) * 496 + n] = p;
                lsum += p;
            }
        }
        atomicAdd(&zsum[b * 496 + n], lsum);
    }
}

// ---------------- Tp[m][d] = sum_n P[m][n] / zsum[n] * Tm[n][d] ------------
__global__ void tp_kernel(const float* __restrict__ S,
                          const float* __restrict__ Tm,
                          const float* __restrict__ zsum,
                          float* __restrict__ Tp)
{
    const int b  = blockIdx.y;
    const int m0 = blockIdx.x * 32;
    const int t  = threadIdx.x;
    const int d  = t & 63, mg = t >> 6;
    __shared__ float As2[32 * 128];
    __shared__ float Ts[128 * 64];
    float acc[8];
#pragma unroll
    for (int j = 0; j < 8; j++) acc[j] = 0.f;

    for (int nc = 0; nc < 512; nc += 128) {
        __syncthreads();
        for (int idx = t; idx < 4096; idx += 256) {
            int r = idx >> 7, cc = idx & 127;
            int m = m0 + r, n = nc + cc;
            As2[idx] = (m < 496 && n < 496)
                          ? S[((size_t)b * 496 + m) * 496 + n] : 0.f;
        }
        for (int idx = t; idx < 8192; idx += 256) {
            int r = idx >> 6, dd = idx & 63;
            int n = nc + r;
            Ts[idx] = (n < 496)
                          ? Tm[((size_t)b * 496 + n) * 64 + dd] / zsum[b * 496 + n]
                          : 0.f;
        }
        __syncthreads();
#pragma unroll 4
        for (int nn = 0; nn < 128; nn++) {
            float tv = Ts[nn * 64 + d];
#pragma unroll
            for (int j = 0; j < 8; j++)
                acc[j] = fmaf(As2[(mg * 8 + j) * 128 + nn], tv, acc[j]);
        }
    }
#pragma unroll
    for (int j = 0; j < 8; j++) {
        int m = m0 + mg * 8 + j;
        if (m < 496) Tp[((size_t)b * 496 + m) * 64 + d] = acc[j];
    }
}

// ---------------- att softmax + rep ----------------------------------------
__global__ void attrep_kernel(const float* __restrict__ E,
                              const float* __restrict__ Tp,
                              const float* __restrict__ attw,
                              const float* __restrict__ attb,
                              float* __restrict__ rep)
{
    const int b = blockIdx.x;
    const int t = threadIdx.x; // 256
    __shared__ float aw[64];
    __shared__ float lg[496];
    __shared__ float att[496];
    __shared__ float redm[4], reds[4];
    __shared__ float part[256];

    if (t < 64) aw[t] = attw[t];
    __syncthreads();
    for (int s = t; s < 496; s += 256) {
        const float* Er = E + ((size_t)b * 496 + s) * 64;
        float a = 0.f;
#pragma unroll
        for (int dd = 0; dd < 64; dd++) a = fmaf(Er[dd], aw[dd], a);
        lg[s] = a + attb[0];
    }
    __syncthreads();
    float m = -1e30f;
    for (int s = t; s < 496; s += 256) m = fmaxf(m, lg[s]);
    for (int off = 32; off > 0; off >>= 1)
        m = fmaxf(m, __shfl_xor(m, off, 64));
    if ((t & 63) == 0) redm[t >> 6] = m;
    __syncthreads();
    m = fmaxf(fmaxf(redm[0], redm[1]), fmaxf(redm[2], redm[3]));
    float sum = 0.f;
    for (int s = t; s < 496; s += 256) {
        float e = __expf(lg[s] - m);
        att[s] = e;
        sum += e;
    }
    for (int off = 32; off > 0; off >>= 1) sum += __shfl_xor(sum, off, 64);
    if ((t & 63) == 0) reds[t >> 6] = sum;
    __syncthreads();
    float inv = 1.f / (reds[0] + reds[1] + reds[2] + reds[3]);

    const int d = t & 63, sg = t >> 6;
    float p = 0.f;
    for (int k = 0; k < 124; k++) {
        int s = sg + 4 * k;
        size_t o = ((size_t)b * 496 + s) * 64 + d;
        p = fmaf(att[s] * inv, fabsf(Tp[o] - E[o]), p);
    }
    part[t] = p;
    __syncthreads();
    if (t < 64)
        rep[b * 64 + t] = part[t] + part[64 + t] + part[128 + t] + part[192 + t];
}

// ---------------- tail MLP --------------------------------------------------
__global__ void mlp_kernel(const float* __restrict__ rep,
                           const float* __restrict__ W3,
                           const float* __restrict__ b3,
                           const float* __restrict__ Wc,
                           const float* __restrict__ bc,
                           float* __restrict__ out)
{
    const int b = blockIdx.x;
    const int t = threadIdx.x; // 128
    __shared__ float hr[64];
    __shared__ float h2[128];
    if (t < 64) hr[t] = fmaxf(rep[b * 64 + t], 0.f);
    __syncthreads();
    float a = b3[t];
#pragma unroll
    for (int d = 0; d < 64; d++) a = fmaf(W3[t * 64 + d], hr[d], a);
    h2[t] = fmaxf(a, 0.f);
    __syncthreads();
    if (t < 2) {
        float o = bc[t];
        for (int k = 0; k < 128; k++) o = fmaf(Wc[t * 128 + k], h2[k], o);
        out[b * 2 + t] = o;
    }
}

// ---------------------------------------------------------------------------
extern "C" void kernel_launch(void* const* d_in, const int* in_sizes, int n_in,
                              void* d_out, int out_size, void* d_ws,
                              size_t ws_size, hipStream_t stream)
{
    const float* ev   = (const float*)d_in[0];
    const float* tmpl = (const float*)d_in[1];
    const float* w1   = (const float*)d_in[2];
    const float* b1   = (const float*)d_in[3];
    const float* w2   = (const float*)d_in[4];
    const float* b2   = (const float*)d_in[5];
    const float* w3   = (const float*)d_in[6];
    const float* b3   = (const float*)d_in[7];
    const float* l1w  = (const float*)d_in[8];
    const float* l1b  = (const float*)d_in[9];
    const float* wih  = (const float*)d_in[10];
    const float* whh  = (const float*)d_in[11];
    const float* bih  = (const float*)d_in[12];
    const float* bhh  = (const float*)d_in[13];
    const float* attw = (const float*)d_in[14];
    const float* attb = (const float*)d_in[15];
    const float* l3w  = (const float*)d_in[16];
    const float* l3b  = (const float*)d_in[17];
    const float* clw  = (const float*)d_in[18];
    const float* clb  = (const float*)d_in[19];

    // ---- persistent region (float units) ----
    float* ws = (float*)d_ws;
    float* xb    = ws;                         // 1,015,808
    float* Eb    = xb + 1015808ull;            // 507,904
    float* Tb    = Eb + 507904ull;
    float* Tpb   = Tb + 507904ull;
    float* repb  = Tpb + 507904ull;            // 1,024
    float* w2pf  = repb + 1024ull;             // 7,680 (15,360 bf16)
    float* w3pf  = w2pf + 7680ull;             // 25,600 (51,200 bf16)
    float* l1wpf = w3pf + 25600ull;            // 131,072 (262,144 bf16)
    float* zsumb = l1wpf + 131072ull;          // 8,192 (16 x 496 used)
    float* arena = zsumb + 8192ull;
    const size_t PERSIST = 2713088ull;

    ushort_t* w2p  = (ushort_t*)w2pf;
    ushort_t* w3p  = (ushort_t*)w3pf;
    ushort_t* l1wp = (ushort_t*)l1wpf;

    // ---- chunk size selection ----
    const int cand[6] = {32, 16, 8, 4, 2, 1};
    int C = 0;
    for (int ci = 0; ci < 6; ci++) {
        size_t a = (size_t)cand[ci] * 2823680ull + 16384ull;
        if (a < 3936256ull) a = 3936256ull;
        if ((PERSIST + a) * sizeof(float) <= ws_size) { C = cand[ci]; break; }
    }
    if (C == 0) return;

    float*    S1 = arena;
    float*    S2 = arena + (size_t)C * 967680ull + 8192ull;
    float*    gib = arena;     // 3,047,424 f (after conv phase)
    float*    Sb  = arena;     // 3,936,256 f (after gru)

    ushort_t* a2  = (ushort_t*)S1;
    ushort_t* pooled = (ushort_t*)S1;  // NCHW-flat, overwrites dead a2
    ushort_t* a1  = (ushort_t*)S2;
    ushort_t* a3h = (ushort_t*)S2;     // (nl,500,58,64) h-pooled conv3 out

    // ---- weight packs + accumulator zeros ----
    hipMemsetAsync(xb, 0, 1015808ull * sizeof(float), stream);
    pack_all<<<256, 256, 0, stream>>>(w2, w3, l1w, w2p, w3p, l1wp, zsumb);

    const int RT = C * 496;
    const int mtiles = (RT + 63) / 64;

    // ---- conv trunk + pool + lin1, chunked ----
    for (int n0 = 0; n0 < 32; n0 += C) {
        conv1_kernel<<<dim3(127, 2, C), 256, 0, stream>>>(ev, tmpl, w1, b1, a1, n0);
        conv_mfma<16, 32, 2, 4, 2, 64, 3, 6, 508, 124, true, false, 4>
            <<<dim3(63, 2, C), 256, 0, stream>>>(a1, w2p, b2, a2);
        conv_mfma<32, 64, 4, 2, 2, 32, 5, 5, 504, 120, false, true, 3>
            <<<dim3(63, 4, C), 256, 0, stream>>>(a2, w3p, b3, a3h);
        pool_fused<<<dim3(31, C), 512, 0, stream>>>(a3h, pooled);
        lin1_mfma<<<dim3(mtiles, 4), 256, 0, stream>>>(pooled, l1wp, xb, n0, RT);
    }

    // ---- GRU ----
    gi_kernel<<<248, 192, 0, stream>>>(xb, wih, bih, l1b, gib);
    gru_kernel<<<992, 192, 0, stream>>>(gib, whh, bhh, Eb, Tb);

    // ---- alignment: scores (+fused colsum, stores exp) -> Tp ----
    scores_kernel<<<dim3(8, 16, 16), 256, 0, stream>>>(Eb, Tb, Sb, zsumb);
    tp_kernel<<<dim3(16, 16), 256, 0, stream>>>(Sb, Tb, zsumb, Tpb);

    // ---- attention + tail ----
    attrep_kernel<<<16, 256, 0, stream>>>(Eb, Tpb, attw, attb, repb);
    mlp_kernel<<<16, 128, 0, stream>>>(repb, l3w, l3b, clw, clb,
                                       (float*)d_out);
}

// Round 12
// 734.455 us; speedup vs baseline: 1.1082x; 1.1082x over previous
//
#include <hip/hip_runtime.h>
#include <hip/hip_bf16.h>
#include <math.h>

// ---------------------------------------------------------------------------
// DeepTemplateMatchingModule — round 27.
// vs round 26 (813.9 us, regression): GRU readlane rewrite reverted (r26:
// VGPR=44 -> w[64] in scratch despite readlane; +8-way gx bank conflict
// 1.77M). Back to the r24 source (763.5 us best) with ONE change: GRU chunk
// 16 -> 31 (7936 = 31 x 256 exactly; 512 blocks x 127 steps vs 992 x 112).
// Rationale from accumulated counters: GRU is issue-bound on warmup
// redundancy (7x at chunk 16; ~91 us floor at 100% VALU issue). Chunk 31
// cuts work to 0.585x at 2 blocks/CU = 6 waves/CU — enough waves for an
// issue-bound kernel (r14's chunk-31 failed at 64-thr/1-wave blocks; 192-thr
// blocks changed that calculus). Structure untouched: three GRU rewrites
// (1-barrier, unbound, readlane) all failed to beat ~119 us — the structure
// was never the bottleneck, the redundant work was.
// ---------------------------------------------------------------------------

#define DEVI static __device__ __forceinline__
typedef __attribute__((ext_vector_type(8))) short short8;
typedef __attribute__((ext_vector_type(4))) float f32x4;
typedef __attribute__((ext_vector_type(8))) float f32x8;
typedef unsigned short ushort_t;

DEVI float fsig(float x)   { return 1.f / (1.f + __expf(-x)); }
DEVI float ftanh_(float x) { return 2.f / (1.f + __expf(-2.f * x)) - 1.f; }
DEVI float bf2f(ushort_t u) { union { unsigned int i; float f; } v; v.i = ((unsigned int)u) << 16; return v.f; }
DEVI ushort_t f2bf(float f) {
    union { float f; unsigned int i; } v; v.f = f;
    unsigned int r = v.i + 0x7FFF + ((v.i >> 16) & 1);
    return (ushort_t)(r >> 16);
}
DEVI f32x8 bf2f8(short8 s) {
    f32x8 r;
#pragma unroll
    for (int k = 0; k < 8; k++) r[k] = bf2f((ushort_t)s[k]);
    return r;
}
DEVI f32x8 max8(f32x8 a, f32x8 b) {
    f32x8 r;
#pragma unroll
    for (int k = 0; k < 8; k++) r[k] = fmaxf(a[k], b[k]);
    return r;
}

// async global->LDS, 16 bytes per lane. LDS dest must be lane-linear
// (wave-uniform base + lane*16); global src is per-lane.
DEVI void glds16(const ushort_t* g, ushort_t* l)
{
    __builtin_amdgcn_global_load_lds(
        (const __attribute__((address_space(1))) void*)g,
        (__attribute__((address_space(3))) void*)l, 16, 0, 0);
}

// ---------------- fused weight packs + zsum zero ---------------------------
// l1wp layout: [r][oct][co] x 8 bf16 — the exact linear order lin1's B-stage
// consumes, so glds16 reads are lane-consecutive.
__global__ void pack_all(const float* __restrict__ w2, const float* __restrict__ w3,
                         const float* __restrict__ l1w,
                         ushort_t* __restrict__ w2p, ushort_t* __restrict__ w3p,
                         ushort_t* __restrict__ l1wp, float* __restrict__ zsum)
{
    const int gid = blockIdx.x * 256 + threadIdx.x;
    const int gsz = gridDim.x * 256;
    for (int idx = gid; idx < 15360; idx += gsz) {
        int kh = idx / 3072, rem = idx % 3072;
        int kw = rem / 512;
        int co = (rem >> 4) & 31, ci = rem & 15;
        float v = (kw < 5) ? w2[((co * 16 + ci) * 5 + kh) * 5 + kw] : 0.f;
        w2p[idx] = f2bf(v);
    }
    for (int idx = gid; idx < 51200; idx += gsz) {
        int kh = idx / 10240, rem = idx % 10240;
        int kw = rem / 2048;
        int co = (rem >> 5) & 63, ci = rem & 31;
        w3p[idx] = f2bf(w3[((co * 32 + ci) * 5 + kh) * 5 + kw]);
    }
    for (int idx = gid; idx < 262144; idx += gsz) {
        int u   = idx & 7;
        int co  = (idx >> 3) & 63;
        int oct = (idx >> 9) & 7;
        int r   = idx >> 12;
        int jj  = oct * 8 + u;
        float v = (jj < 58) ? l1w[co * 3712 + r * 58 + jj] : 0.f;
        l1wp[idx] = f2bf(v);
    }
    for (int idx = gid; idx < 8192; idx += gsz) zsum[idx] = 0.f;
}

// ---------------- conv1: direct from eval/template, writes NHWC bf16 -------
__global__ void conv1_kernel(const float* __restrict__ ev,
                             const float* __restrict__ tmpl,
                             const float* __restrict__ wgt,
                             const float* __restrict__ bias,
                             ushort_t* __restrict__ out, int n0)
{
    const int h0  = blockIdx.x * 4;
    const int w0  = blockIdx.y * 62;
    const int nl  = blockIdx.z;
    const int n   = n0 + nl;
    const int tid = threadIdx.x;
    const int wl  = tid & 63;
    const int cg  = tid >> 6;
    const float* src = (n < 16) ? (ev + (size_t)n * 65536)
                                : (tmpl + (size_t)(n - 16) * 65536);

    __shared__ float tin[8 * 68];
    __shared__ float tw[16 * 25];

    float acc[4][4];
#pragma unroll
    for (int j = 0; j < 4; j++)
#pragma unroll
        for (int hh = 0; hh < 4; hh++) acc[j][hh] = 0.f;

    for (int idx = tid; idx < 528; idx += 256) {
        int cc = idx >> 3, r = idx & 7;
        tin[r * 68 + cc] = src[(w0 + cc) * 512 + h0 + r];
    }
    for (int idx = tid; idx < 400; idx += 256) tw[idx] = wgt[idx];
    __syncthreads();
#pragma unroll
    for (int kh = 0; kh < 5; kh++) {
#pragma unroll
        for (int kw = 0; kw < 5; kw++) {
            float iv[4];
#pragma unroll
            for (int hh = 0; hh < 4; hh++)
                iv[hh] = tin[(hh + kh) * 68 + wl + kw];
#pragma unroll
            for (int j = 0; j < 4; j++) {
                float wv = tw[(cg * 4 + j) * 25 + kh * 5 + kw];
#pragma unroll
                for (int hh = 0; hh < 4; hh++)
                    acc[j][hh] = fmaf(wv, iv[hh], acc[j][hh]);
            }
        }
    }
    if (wl < 62) {
#pragma unroll
        for (int hh = 0; hh < 4; hh++) {
            ushort_t pk[4];
#pragma unroll
            for (int j = 0; j < 4; j++)
                pk[j] = f2bf(acc[j][hh] + bias[cg * 4 + j]);
            ushort_t* dst = out + ((size_t)(nl * 508 + h0 + hh) * 124 + w0 + wl) * 16 + cg * 4;
            *(uint2*)dst = *(uint2*)pk;
        }
    }
}

// ---------------- MFMA implicit-GEMM 5x5 conv (r23 layout, opt. h-pool) ----
template<int CI, int CO, int NF, int MF, int NHI, int W_T, int KSTEPS,
         int KW_TOT, int H_IN, int W_IN, bool PAD2, bool HPOOL, int MAXB>
__global__ __launch_bounds__(256, MAXB) void conv_mfma(
    const ushort_t* __restrict__ in, const ushort_t* __restrict__ wpk,
    const float* __restrict__ bias, ushort_t* __restrict__ out)
{
    constexpr int H_OUT = H_IN - 4;
    constexpr int W_OUT = W_IN - 4;
    constexpr int HALO  = W_T + 6;
    constexpr int OCT   = CI / 8;
    constexpr int AROWS = 4 * NHI + 4;
    constexpr int APL   = AROWS * HALO;
    constexpr int BPL   = KW_TOT * CO;
    constexpr int BTOT  = OCT * BPL;
    constexpr int BSTG  = (BTOT + 255) / 256;
    constexpr int KHOFF = KW_TOT * CO * CI;   // element offset per kh row

    const int h0 = blockIdx.x * (4 * NHI);
    const int w0 = blockIdx.y * W_T;
    const int nl = blockIdx.z;
    const int tid  = threadIdx.x;
    const int wv   = tid >> 6;
    const int lane = tid & 63;
    const int l16  = lane & 15;
    const int kq   = lane >> 4;

    __shared__ __align__(16) ushort_t As[OCT * APL * 8];
    __shared__ __align__(16) ushort_t Bs[BTOT * 8];

    f32x4 acc[NHI][MF][NF];
#pragma unroll
    for (int hi = 0; hi < NHI; hi++)
#pragma unroll
        for (int mi = 0; mi < MF; mi++)
#pragma unroll
            for (int ni = 0; ni < NF; ni++)
                acc[hi][mi][ni] = f32x4{0.f, 0.f, 0.f, 0.f};

    // A tile staged once
    for (int idx = tid; idx < OCT * APL; idx += 256) {
        int oct = idx / APL, e = idx - oct * APL;
        int r = e / HALO, c = e - r * HALO;
        glds16(in + ((size_t)((nl * H_IN + h0 + r) * W_IN + w0 + c)) * CI + oct * 8,
               &As[idx * 8]);
    }

    // B staging addresses hoisted: computed once, reused for all 5 kh rows
    const ushort_t* bsrc[BSTG];
    ushort_t*       bdst[BSTG];
#pragma unroll
    for (int sb = 0; sb < BSTG; sb++) {
        int idx = tid + sb * 256;
        if (idx < BTOT) {
            int oct = idx / BPL, e = idx - oct * BPL;
            int kw = e / CO, co = e - kw * CO;
            bsrc[sb] = wpk + ((size_t)(kw * CO + co)) * CI + oct * 8;
            bdst[sb] = &Bs[idx * 8];
        } else { bsrc[sb] = nullptr; bdst[sb] = nullptr; }
    }

    const int aoct = PAD2 ? (kq & 1) : kq;
    const int kwq  = PAD2 ? (kq >> 1) : 0;

#pragma unroll
    for (int kh = 0; kh < 5; kh++) {
        __syncthreads();
#pragma unroll
        for (int sb = 0; sb < BSTG; sb++)
            if (bsrc[sb]) glds16(bsrc[sb] + kh * KHOFF, bdst[sb]);
        __syncthreads();
#pragma unroll
        for (int st = 0; st < KSTEPS; st++) {
            const int colq = (PAD2 ? st * 2 : st) + kwq;
            short8 bfv[NF];
#pragma unroll
            for (int ni = 0; ni < NF; ni++)
                bfv[ni] = *(const short8*)&Bs[(aoct * BPL + colq * CO + ni * 16 + l16) * 8];
#pragma unroll
            for (int hi = 0; hi < NHI; hi++) {
                short8 af[MF];
#pragma unroll
                for (int mi = 0; mi < MF; mi++)
                    af[mi] = *(const short8*)&As[(aoct * APL + (hi * 4 + wv + kh) * HALO + mi * 16 + l16 + colq) * 8];
#pragma unroll
                for (int mi = 0; mi < MF; mi++)
#pragma unroll
                    for (int ni = 0; ni < NF; ni++)
                        acc[hi][mi][ni] = __builtin_amdgcn_mfma_f32_16x16x32_bf16(
                            af[mi], bfv[ni], acc[hi][mi][ni], 0, 0, 0);
            }
        }
    }

#pragma unroll
    for (int hi = 0; hi < NHI; hi++) {
        const int h = h0 + hi * 4 + wv;
        if (h < H_OUT) {
#pragma unroll
            for (int mi = 0; mi < MF; mi++) {
#pragma unroll
                for (int ni = 0; ni < NF; ni++) {
                    int co = ni * 16 + l16;
                    float bv = bias[co];
                    if constexpr (HPOOL) {
                        const int jw = (w0 + mi * 16 + kq * 4) >> 1;
                        if (jw < 58)
                            out[((size_t)(nl * H_OUT + h) * 58 + jw) * CO + co] =
                                f2bf(fmaxf(acc[hi][mi][ni][0], acc[hi][mi][ni][1]) + bv);
                        if (jw + 1 < 58)
                            out[((size_t)(nl * H_OUT + h) * 58 + jw + 1) * CO + co] =
                                f2bf(fmaxf(acc[hi][mi][ni][2], acc[hi][mi][ni][3]) + bv);
                    } else {
#pragma unroll
                        for (int reg = 0; reg < 4; reg++) {
                            int w = w0 + mi * 16 + kq * 4 + reg;
                            if (w < W_OUT)
                                out[((size_t)(nl * H_OUT + h) * W_OUT + w) * CO + co] =
                                    f2bf(acc[hi][mi][ni][reg] + bv);
                        }
                    }
                }
            }
        }
    }
}

// ---------------- fused pool: vertical 5-max + transpose -> NCHW-flat ------
__global__ __launch_bounds__(512) void pool_fused(const ushort_t* __restrict__ a3h,
                                                  ushort_t* __restrict__ pooled)
{
    const int nl = blockIdx.y;
    const int s0 = blockIdx.x * 16;      // 31 blocks x 16 = 496
    const int t  = threadIdx.x;
    __shared__ ushort_t L[4 * 3712];

    const int j = t >> 3, oct = t & 7;
    const ushort_t* base = a3h + (size_t)nl * 1856000 + (size_t)j * 64 + oct * 8;
    ushort_t* dst = pooled + (size_t)nl * 1841152;

#define LOADROW(rr) bf2f8(*(const short8*)(base + (size_t)(rr) * 3712))
    f32x8 w0, w1, w2v, w3v;
    if (t < 464) {
        w0  = LOADROW(s0);
        w1  = LOADROW(s0 + 1);
        w2v = LOADROW(s0 + 2);
        w3v = LOADROW(s0 + 3);
    }
    for (int g = 0; g < 4; g++) {
        if (t < 464) {
#pragma unroll
            for (int k = 0; k < 4; k++) {
                int s = s0 + g * 4 + k;
                f32x8 w4 = LOADROW(s + 4);
                f32x8 mx = max8(max8(max8(w0, w1), max8(w2v, w3v)), w4);
#pragma unroll
                for (int u = 0; u < 8; u++)
                    L[k * 3712 + (oct * 8 + u) * 58 + j] = f2bf(mx[u]);
                w0 = w1; w1 = w2v; w2v = w3v; w3v = w4;
            }
        }
        __syncthreads();
        const int sg = s0 + g * 4;
        for (int e = t; e < 14848; e += 512) {
            int k = e / 3712, r = e - k * 3712;
            int c = r / 58, jj = r - c * 58;
            dst[(size_t)c * 28768 + (sg + k) * 58 + jj] = L[e];
        }
        __syncthreads();
    }
#undef LOADROW
}

// ---------------- lin1: M=64 N=64 K=1024/block MFMA, k-split x4 ------------
__global__ __launch_bounds__(256) void lin1_mfma(
    const ushort_t* __restrict__ pooled, const ushort_t* __restrict__ l1wp,
    float* __restrict__ xb, int n0, int RT)
{
    const int mt  = blockIdx.x;
    const int kqb = blockIdx.y;          // 4 k-quarters
    const int r0  = mt * 64;
    const int t   = threadIdx.x;
    const int wv  = t >> 6, lane = t & 63, l16 = lane & 15, kq = lane >> 4;

    __shared__ __align__(16) ushort_t As[8 * 64 * 8];  // [oct][row]
    __shared__ __align__(16) ushort_t Bs[8 * 64 * 8];  // [oct][co]

    f32x4 acc[4];
#pragma unroll
    for (int ni = 0; ni < 4; ni++) acc[ni] = f32x4{0.f, 0.f, 0.f, 0.f};

    for (int kb = 0; kb < 16; kb++) {
        const int k0 = kqb * 1024 + kb * 64;
        const int r  = k0 >> 6;
        __syncthreads();
        // A: coalesced — 8 lanes (oct 0..7) read 128B contiguous per row
        for (int idx = t; idx < 512; idx += 256) {
            int row = idx >> 3, oct = idx & 7;
            int rr = r0 + row;
            short8 v = short8{0, 0, 0, 0, 0, 0, 0, 0};
            if (rr < RT)
                v = *(const short8*)(pooled + (size_t)rr * 3712 + r * 58 + oct * 8);
            *(short8*)&As[(oct * 64 + row) * 8] = v;
        }
        // B: l1wp packed in staging-linear order [r][oct][co] -> glds16
        // sources are lane-consecutive, dest is lane-linear.
        for (int idx = t; idx < 512; idx += 256)
            glds16(l1wp + ((size_t)r * 512 + idx) * 8, &Bs[idx * 8]);
        __syncthreads();
#pragma unroll
        for (int st = 0; st < 2; st++) {
            short8 af = *(const short8*)&As[((st * 4 + kq) * 64 + wv * 16 + l16) * 8];
#pragma unroll
            for (int ni = 0; ni < 4; ni++) {
                short8 bfv = *(const short8*)&Bs[((st * 4 + kq) * 64 + ni * 16 + l16) * 8];
                acc[ni] = __builtin_amdgcn_mfma_f32_16x16x32_bf16(af, bfv, acc[ni], 0, 0, 0);
            }
        }
    }
#pragma unroll
    for (int ni = 0; ni < 4; ni++) {
        int co = ni * 16 + l16;
#pragma unroll
        for (int reg = 0; reg < 4; reg++) {
            int rr = r0 + wv * 16 + kq * 4 + reg;
            if (rr < RT)
                atomicAdd(&xb[((size_t)n0 * 496 + rr) * 64 + co], acc[ni][reg]);
        }
    }
}

// ---------------- gi = (x + l1b) @ W_ih^T + b_ih  (coalesced W staging) ----
__global__ __launch_bounds__(192) void gi_kernel(
    const float* __restrict__ x, const float* __restrict__ Wih,
    const float* __restrict__ bih, const float* __restrict__ l1b,
    float* __restrict__ gi)
{
    const int r0 = blockIdx.x * 64;
    const int j  = threadIdx.x; // 192
    __shared__ float wls[192 * 65];
    __shared__ float xl[64 * 64];

    for (int idx = j; idx < 12288; idx += 192)
        wls[(idx >> 6) * 65 + (idx & 63)] = Wih[idx];
    for (int idx = j; idx < 4096; idx += 192)
        xl[idx] = x[(size_t)r0 * 64 + idx] + l1b[idx & 63];
    __syncthreads();

    float w[64];
#pragma unroll
    for (int d = 0; d < 64; d++) w[d] = wls[j * 65 + d];
    const float bj = bih[j];

    for (int s = 0; s < 64; s++) {
        float a = bj;
#pragma unroll
        for (int d = 0; d < 64; d++) a = fmaf(w[d], xl[s * 64 + d], a);
        gi[(size_t)(r0 + s) * 192 + j] = a;
    }
}

// ---------------- chunk-parallel GRU: 512 blocks x 192 thr, 31-step chunks -
// r24 structure (proven): one barrier per step, gs/gnl double-buffered, all
// 3 waves redundantly compute the combine, per-wave hsw float4 broadcast.
// Chunk 31 (7936 = 31 x 256): 127 steps per block vs 112 at chunk 16, but
// 0.585x total work — GRU is issue-bound on warmup redundancy.
__global__ __launch_bounds__(192, 3) void gru_kernel(
    const float* __restrict__ gi, const float* __restrict__ Whh,
    const float* __restrict__ bhh, float* __restrict__ Eo,
    float* __restrict__ To)
{
    const int c  = blockIdx.x;          // 512 = 2 x 256
    const int br = (c >= 256) ? 1 : 0;
    const int q  = c - br * 256;
    const int j  = threadIdx.x;         // 0..191
    const int wvid = j >> 6;            // wave 0..2
    const int u    = j & 63;            // unit id
    const float* gb = gi + (size_t)br * 7936 * 192;
    float* out = br ? To : Eo;

    float w[64];
#pragma unroll
    for (int k = 0; k < 64; k++) w[k] = Whh[j * 64 + k];
    const float bh = bhh[j];

    __shared__ float gs[2][192];
    __shared__ float gnl[2][64];
    __shared__ __align__(16) float hsw[3][64];

    float h[64];
#pragma unroll
    for (int k = 0; k < 64; k++) h[k] = 0.f;
    float hown = 0.f;                   // h[u], tracked per-thread

    const int cs  = q * 31;
    int start = cs - 96;
    if (start < 0) start = 0;
    const int end = cs + 31;

    const bool isN = (j >= 128);

    float pg[4];
#pragma unroll
    for (int uu = 0; uu < 4; uu++) {
        int s = start + uu;
        pg[uu] = (s < end) ? gb[(size_t)s * 192 + j] : 0.f;
    }

    int s = start;
    int buf = 0;
    while (s < end) {
#pragma unroll
        for (int uu = 0; uu < 4; uu++) {
            if (s < end) {
                float g = pg[uu];
                int sp = s + 4;
                if (sp < end) pg[uu] = gb[(size_t)sp * 192 + j];
                float a0 = bh, a1 = 0.f;
#pragma unroll
                for (int k = 0; k < 64; k += 2) {
                    a0 = fmaf(w[k],     h[k],     a0);
                    a1 = fmaf(w[k + 1], h[k + 1], a1);
                }
                float gh = a0 + a1;
                gs[buf][j] = isN ? gh : (gh + g);
                if (isN) gnl[buf][j - 128] = g;
                __syncthreads();
                // every wave computes the combine for its unit u
                float r  = fsig(gs[buf][u]);
                float z  = fsig(gs[buf][64 + u]);
                float nv = ftanh_(gnl[buf][u] + r * gs[buf][128 + u]);
                float hn = (1.f - z) * nv + z * hown;
                hown = hn;
                hsw[wvid][u] = hn;
#pragma unroll
                for (int k = 0; k < 16; k++) {
                    float4 v = ((const float4*)hsw[wvid])[k];
                    h[4 * k + 0] = v.x; h[4 * k + 1] = v.y;
                    h[4 * k + 2] = v.z; h[4 * k + 3] = v.w;
                }
                if (wvid == 0 && s >= cs) out[(size_t)s * 64 + u] = hn;
                buf ^= 1;
                s++;
            }
        }
    }
}

// ---------------- scores + fused column exp-sum (stores P = exp(S)) --------
__global__ void scores_kernel(const float* __restrict__ E,
                              const float* __restrict__ Tm,
                              float* __restrict__ S,
                              float* __restrict__ zsum)
{
    const int b  = blockIdx.z;
    const int m0 = blockIdx.y * 32;
    const int n0 = blockIdx.x * 64;
    const int t  = threadIdx.x;
    const int nl = t & 63, mg = t >> 6;
    __shared__ float El[32 * 64];
    __shared__ float Tms[64 * 65];

    for (int idx = t; idx < 2048; idx += 256) {
        int r = idx >> 6, d = idx & 63;
        int m = m0 + r;
        El[idx] = (m < 496) ? E[((size_t)b * 496 + m) * 64 + d] : 0.f;
    }
    for (int idx = t; idx < 4096; idx += 256) {
        int r = idx >> 6, d = idx & 63;
        int n = n0 + r;
        Tms[d * 65 + r] = (n < 496) ? Tm[((size_t)b * 496 + n) * 64 + d] : 0.f;
    }
    __syncthreads();

    float acc[8];
#pragma unroll
    for (int j = 0; j < 8; j++) acc[j] = 0.f;
#pragma unroll 4
    for (int d = 0; d < 64; d++) {
        float tv = Tms[d * 65 + nl];
#pragma unroll
        for (int j = 0; j < 8; j++)
            acc[j] = fmaf(El[(mg * 8 + j) * 64 + d], tv, acc[j]);
    }
    int n = n0 + nl;
    if (n < 496) {
        float lsum = 0.f;
#pragma unroll
        for (int j = 0; j < 8; j++) {
            int m = m0 + mg * 8 + j;
            if (m < 496) {
                float p = __expf(acc[j]);
                S[((size_t)b * 496 + m) * 496 + n] = p;
                lsum += p;
            }
        }
        atomicAdd(&zsum[b * 496 + n], lsum);
    }
}

// ---------------- Tp[m][d] = sum_n P[m][n] / zsum[n] * Tm[n][d] ------------
__global__ void tp_kernel(const float* __restrict__ S,
                          const float* __restrict__ Tm,
                          const float* __restrict__ zsum,
                          float* __restrict__ Tp)
{
    const int b  = blockIdx.y;
    const int m0 = blockIdx.x * 32;
    const int t  = threadIdx.x;
    const int d  = t & 63, mg = t >> 6;
    __shared__ float As2[32 * 128];
    __shared__ float Ts[128 * 64];
    float acc[8];
#pragma unroll
    for (int j = 0; j < 8; j++) acc[j] = 0.f;

    for (int nc = 0; nc < 512; nc += 128) {
        __syncthreads();
        for (int idx = t; idx < 4096; idx += 256) {
            int r = idx >> 7, cc = idx & 127;
            int m = m0 + r, n = nc + cc;
            As2[idx] = (m < 496 && n < 496)
                          ? S[((size_t)b * 496 + m) * 496 + n] : 0.f;
        }
        for (int idx = t; idx < 8192; idx += 256) {
            int r = idx >> 6, dd = idx & 63;
            int n = nc + r;
            Ts[idx] = (n < 496)
                          ? Tm[((size_t)b * 496 + n) * 64 + dd] / zsum[b * 496 + n]
                          : 0.f;
        }
        __syncthreads();
#pragma unroll 4
        for (int nn = 0; nn < 128; nn++) {
            float tv = Ts[nn * 64 + d];
#pragma unroll
            for (int j = 0; j < 8; j++)
                acc[j] = fmaf(As2[(mg * 8 + j) * 128 + nn], tv, acc[j]);
        }
    }
#pragma unroll
    for (int j = 0; j < 8; j++) {
        int m = m0 + mg * 8 + j;
        if (m < 496) Tp[((size_t)b * 496 + m) * 64 + d] = acc[j];
    }
}

// ---------------- att softmax + rep ----------------------------------------
__global__ void attrep_kernel(const float* __restrict__ E,
                              const float* __restrict__ Tp,
                              const float* __restrict__ attw,
                              const float* __restrict__ attb,
                              float* __restrict__ rep)
{
    const int b = blockIdx.x;
    const int t = threadIdx.x; // 256
    __shared__ float aw[64];
    __shared__ float lg[496];
    __shared__ float att[496];
    __shared__ float redm[4], reds[4];
    __shared__ float part[256];

    if (t < 64) aw[t] = attw[t];
    __syncthreads();
    for (int s = t; s < 496; s += 256) {
        const float* Er = E + ((size_t)b * 496 + s) * 64;
        float a = 0.f;
#pragma unroll
        for (int dd = 0; dd < 64; dd++) a = fmaf(Er[dd], aw[dd], a);
        lg[s] = a + attb[0];
    }
    __syncthreads();
    float m = -1e30f;
    for (int s = t; s < 496; s += 256) m = fmaxf(m, lg[s]);
    for (int off = 32; off > 0; off >>= 1)
        m = fmaxf(m, __shfl_xor(m, off, 64));
    if ((t & 63) == 0) redm[t >> 6] = m;
    __syncthreads();
    m = fmaxf(fmaxf(redm[0], redm[1]), fmaxf(redm[2], redm[3]));
    float sum = 0.f;
    for (int s = t; s < 496; s += 256) {
        float e = __expf(lg[s] - m);
        att[s] = e;
        sum += e;
    }
    for (int off = 32; off > 0; off >>= 1) sum += __shfl_xor(sum, off, 64);
    if ((t & 63) == 0) reds[t >> 6] = sum;
    __syncthreads();
    float inv = 1.f / (reds[0] + reds[1] + reds[2] + reds[3]);

    const int d = t & 63, sg = t >> 6;
    float p = 0.f;
    for (int k = 0; k < 124; k++) {
        int s = sg + 4 * k;
        size_t o = ((size_t)b * 496 + s) * 64 + d;
        p = fmaf(att[s] * inv, fabsf(Tp[o] - E[o]), p);
    }
    part[t] = p;
    __syncthreads();
    if (t < 64)
        rep[b * 64 + t] = part[t] + part[64 + t] + part[128 + t] + part[192 + t];
}

// ---------------- tail MLP --------------------------------------------------
__global__ void mlp_kernel(const float* __restrict__ rep,
                           const float* __restrict__ W3,
                           const float* __restrict__ b3,
                           const float* __restrict__ Wc,
                           const float* __restrict__ bc,
                           float* __restrict__ out)
{
    const int b = blockIdx.x;
    const int t = threadIdx.x; // 128
    __shared__ float hr[64];
    __shared__ float h2[128];
    if (t < 64) hr[t] = fmaxf(rep[b * 64 + t], 0.f);
    __syncthreads();
    float a = b3[t];
#pragma unroll
    for (int d = 0; d < 64; d++) a = fmaf(W3[t * 64 + d], hr[d], a);
    h2[t] = fmaxf(a, 0.f);
    __syncthreads();
    if (t < 2) {
        float o = bc[t];
        for (int k = 0; k < 128; k++) o = fmaf(Wc[t * 128 + k], h2[k], o);
        out[b * 2 + t] = o;
    }
}

// ---------------------------------------------------------------------------
extern "C" void kernel_launch(void* const* d_in, const int* in_sizes, int n_in,
                              void* d_out, int out_size, void* d_ws,
                              size_t ws_size, hipStream_t stream)
{
    const float* ev   = (const float*)d_in[0];
    const float* tmpl = (const float*)d_in[1];
    const float* w1   = (const float*)d_in[2];
    const float* b1   = (const float*)d_in[3];
    const float* w2   = (const float*)d_in[4];
    const float* b2   = (const float*)d_in[5];
    const float* w3   = (const float*)d_in[6];
    const float* b3   = (const float*)d_in[7];
    const float* l1w  = (const float*)d_in[8];
    const float* l1b  = (const float*)d_in[9];
    const float* wih  = (const float*)d_in[10];
    const float* whh  = (const float*)d_in[11];
    const float* bih  = (const float*)d_in[12];
    const float* bhh  = (const float*)d_in[13];
    const float* attw = (const float*)d_in[14];
    const float* attb = (const float*)d_in[15];
    const float* l3w  = (const float*)d_in[16];
    const float* l3b  = (const float*)d_in[17];
    const float* clw  = (const float*)d_in[18];
    const float* clb  = (const float*)d_in[19];

    // ---- persistent region (float units) ----
    float* ws = (float*)d_ws;
    float* xb    = ws;                         // 1,015,808
    float* Eb    = xb + 1015808ull;            // 507,904
    float* Tb    = Eb + 507904ull;
    float* Tpb   = Tb + 507904ull;
    float* repb  = Tpb + 507904ull;            // 1,024
    float* w2pf  = repb + 1024ull;             // 7,680 (15,360 bf16)
    float* w3pf  = w2pf + 7680ull;             // 25,600 (51,200 bf16)
    float* l1wpf = w3pf + 25600ull;            // 131,072 (262,144 bf16)
    float* zsumb = l1wpf + 131072ull;          // 8,192 (16 x 496 used)
    float* arena = zsumb + 8192ull;
    const size_t PERSIST = 2713088ull;

    ushort_t* w2p  = (ushort_t*)w2pf;
    ushort_t* w3p  = (ushort_t*)w3pf;
    ushort_t* l1wp = (ushort_t*)l1wpf;

    // ---- chunk size selection ----
    const int cand[6] = {32, 16, 8, 4, 2, 1};
    int C = 0;
    for (int ci = 0; ci < 6; ci++) {
        size_t a = (size_t)cand[ci] * 2823680ull + 16384ull;
        if (a < 3936256ull) a = 3936256ull;
        if ((PERSIST + a) * sizeof(float) <= ws_size) { C = cand[ci]; break; }
    }
    if (C == 0) return;

    float*    S1 = arena;
    float*    S2 = arena + (size_t)C * 967680ull + 8192ull;
    float*    gib = arena;     // 3,047,424 f (after conv phase)
    float*    Sb  = arena;     // 3,936,256 f (after gru)

    ushort_t* a2  = (ushort_t*)S1;
    ushort_t* pooled = (ushort_t*)S1;  // NCHW-flat, overwrites dead a2
    ushort_t* a1  = (ushort_t*)S2;
    ushort_t* a3h = (ushort_t*)S2;     // (nl,500,58,64) h-pooled conv3 out

    // ---- weight packs + accumulator zeros ----
    hipMemsetAsync(xb, 0, 1015808ull * sizeof(float), stream);
    pack_all<<<256, 256, 0, stream>>>(w2, w3, l1w, w2p, w3p, l1wp, zsumb);

    const int RT = C * 496;
    const int mtiles = (RT + 63) / 64;

    // ---- conv trunk + pool + lin1, chunked ----
    for (int n0 = 0; n0 < 32; n0 += C) {
        conv1_kernel<<<dim3(127, 2, C), 256, 0, stream>>>(ev, tmpl, w1, b1, a1, n0);
        conv_mfma<16, 32, 2, 4, 2, 64, 3, 6, 508, 124, true, false, 4>
            <<<dim3(63, 2, C), 256, 0, stream>>>(a1, w2p, b2, a2);
        conv_mfma<32, 64, 4, 2, 2, 32, 5, 5, 504, 120, false, true, 3>
            <<<dim3(63, 4, C), 256, 0, stream>>>(a2, w3p, b3, a3h);
        pool_fused<<<dim3(31, C), 512, 0, stream>>>(a3h, pooled);
        lin1_mfma<<<dim3(mtiles, 4), 256, 0, stream>>>(pooled, l1wp, xb, n0, RT);
    }

    // ---- GRU ----
    gi_kernel<<<248, 192, 0, stream>>>(xb, wih, bih, l1b, gib);
    gru_kernel<<<512, 192, 0, stream>>>(gib, whh, bhh, Eb, Tb);

    // ---- alignment: scores (+fused colsum, stores exp) -> Tp ----
    scores_kernel<<<dim3(8, 16, 16), 256, 0, stream>>>(Eb, Tb, Sb, zsumb);
    tp_kernel<<<dim3(16, 16), 256, 0, stream>>>(Sb, Tb, zsumb, Tpb);

    // ---- attention + tail ----
    attrep_kernel<<<16, 256, 0, stream>>>(Eb, Tpb, attw, attb, repb);
    mlp_kernel<<<16, 128, 0, stream>>>(repb, l3w, l3b, clw, clb,
                                       (float*)d_out);
}